// Round 12
// baseline (117.115 us; speedup 1.0000x reference)
//
#include <hip/hip_runtime.h>
#include <hip/hip_bf16.h>
#include <math.h>

#define ALPHA 0.25f
#define EPS 1e-8f
#define BQ_TILE 16

// ---------------------------------------------------------------------------
// Kernel 1: prep tables.
//  (a) per-(bq,c) focal class cost with GIoU-identity "+1" baked in
//  (b) per-bq pred corners {px0,py0,px1,py1}
// ---------------------------------------------------------------------------
__global__ __launch_bounds__(256) void prep_kernel(
    const float* __restrict__ logits,     // [BQ*C]
    const float* __restrict__ pred_bbox,  // [BQ,4]
    float* __restrict__ cc,               // [BQ*C] out: class cost + 1
    float4* __restrict__ pcorn,           // [BQ]   out: corners
    int n_cc, int BQ)
{
    int i = blockIdx.x * 256 + threadIdx.x;
    if (i < n_cc) {
        float x = logits[i];
        float p = 1.0f / (1.0f + expf(-x));
        float om = 1.0f - p;
        float pos = ALPHA * om * om * (-logf(p + EPS));
        float neg = (1.0f - ALPHA) * p * p * (-logf(om + EPS));
        cc[i] = pos - neg + 1.0f;
    }
    if (i < BQ) {
        float4 pb = reinterpret_cast<const float4*>(pred_bbox)[i];
        float4 c;
        c.x = pb.x - 0.5f * pb.z;
        c.y = pb.y - 0.5f * pb.w;
        c.z = pb.x + 0.5f * pb.z;
        c.w = pb.y + 0.5f * pb.w;
        pcorn[i] = c;
    }
}

// ---------------------------------------------------------------------------
// Kernel 2: pairwise cost [BQ, T].
//   cost = l1 + (cls+1) - (inter*ae + u^2)/(u*ae)   (exact; EPS terms cancel)
// Wave-unit decomposition; wu is readfirstlane'd to an SGPR so the compiler's
// uniformity analysis sees bq0/tc as wave-uniform -> pred-side loads go back
// to the pipelined scalar s_load path (they regressed to per-lane VMEM when
// wu derived from threadIdx.x>>6).
// ---------------------------------------------------------------------------
__global__ __launch_bounds__(256) void cost_kernel(
    const float* __restrict__ pred_bbox,  // [BQ,4] cxcywh
    const float4* __restrict__ pcorn,     // [BQ]   corners
    const float* __restrict__ tgt_bbox,   // [T,4]  cxcywh
    const int*   __restrict__ labels,     // [T]
    const float* __restrict__ cc,         // [BQ,4] class cost + 1
    float* __restrict__ out,              // [BQ,T]
    int BQ, int T, int nTC, int nWU)
{
    __shared__ float s_cc[4 * BQ_TILE * 4];   // [wave][16 bq][4 classes]

    int wslot = threadIdx.x >> 6;
    int lane  = threadIdx.x & 63;
    int wu = blockIdx.x * 4 + wslot;
    wu = __builtin_amdgcn_readfirstlane(wu);   // SGPR: restores scalar loads
    if (wu >= nWU) return;
    int tc  = wu % nTC;          // t-chunk (64 tgroups each)   [SALU]
    int bqt = wu / nTC;          // bq tile (16 rows)           [SALU]
    int bq0 = bqt * BQ_TILE;

    // stage this wave's 64-float class-cost slice (same-wave use -> no barrier)
    s_cc[wslot * 64 + lane] = cc[bq0 * 4 + lane];

    int tg = tc * 64 + lane;     // target-group index (4 targets each)
    int TG = T >> 2;
    if (tg >= TG) return;
    int t0 = tg * 4;

    // ---- target-side setup: 4 targets per thread (hoisted) ----
    float4 tb[4];
    float tx0[4], ty0[4], tx1[4], ty1[4], a2e[4];
    int lidx[4];
    int4 lv = reinterpret_cast<const int4*>(labels)[tg];
    int lbl[4] = {lv.x, lv.y, lv.z, lv.w};
    #pragma unroll
    for (int j = 0; j < 4; ++j) {
        tb[j] = reinterpret_cast<const float4*>(tgt_bbox)[t0 + j];
        tx0[j] = tb[j].x - 0.5f * tb[j].z;
        ty0[j] = tb[j].y - 0.5f * tb[j].w;
        tx1[j] = tb[j].x + 0.5f * tb[j].z;
        ty1[j] = tb[j].y + 0.5f * tb[j].w;
        a2e[j] = tb[j].z * tb[j].w + EPS;        // area2 + EPS pre-folded
        lidx[j] = wslot * 64 + lbl[j];           // LDS gather base (bq adds i*4)
    }

    #pragma unroll
    for (int i = 0; i < BQ_TILE; ++i) {          // no break: BQ % 16 == 0
        int bq = bq0 + i;
        // wave-uniform -> s_load_dwordx4 pair, pipelined across the unroll
        float4 pb = reinterpret_cast<const float4*>(pred_bbox)[bq];
        float4 pc = pcorn[bq];
        float area1 = pb.z * pb.w;

        float r[4];
        #pragma unroll
        for (int j = 0; j < 4; ++j) {
            // class cost (+1): LDS gather, immediate offset i*16B, 0 VALU
            float cls = s_cc[lidx[j] + i * 4];

            // L1 on cxcywh
            float l1 = (fabsf(pb.x - tb[j].x) + fabsf(pb.y - tb[j].y))
                     + (fabsf(pb.z - tb[j].z) + fabsf(pb.w - tb[j].w));

            // intersection (raw widths kept for enclosing-box identity)
            float iwr = fminf(pc.z, tx1[j]) - fmaxf(pc.x, tx0[j]);
            float ihr = fminf(pc.w, ty1[j]) - fmaxf(pc.y, ty0[j]);
            float iw = fmaxf(iwr, 0.0f);
            float ih = fmaxf(ihr, 0.0f);
            float inter = iw * ih;

            // enclosing box via min+max=sum identity
            float ew = (pb.z + tb[j].z) - iwr;
            float eh = (pb.w + tb[j].w) - ihr;
            float ae = fmaf(ew, eh, EPS);        // area_e + EPS

            float u = (area1 + a2e[j]) - inter;  // union + EPS

            // inter/u + u/ae == (inter*ae + u*u)/(u*ae) -- one rcp
            float num = fmaf(inter, ae, u * u);
            float q = num * __builtin_amdgcn_rcpf(u * ae);

            r[j] = (l1 + cls) - q;
        }
        *reinterpret_cast<float4*>(&out[(size_t)bq * T + t0]) =
            make_float4(r[0], r[1], r[2], r[3]);
    }
}

extern "C" void kernel_launch(void* const* d_in, const int* in_sizes, int n_in,
                              void* d_out, int out_size, void* d_ws, size_t ws_size,
                              hipStream_t stream) {
    const float* logits    = (const float*)d_in[0];  // [B,Q,C]
    const float* pred_bbox = (const float*)d_in[1];  // [B,Q,4]
    const float* tgt_bbox  = (const float*)d_in[2];  // [T,4]
    const int*   labels    = (const int*)d_in[3];    // [T]

    int BQ = in_sizes[1] / 4;          // 14400
    int T  = in_sizes[3];              // 1600

    float*  cc    = (float*)d_ws;                    // [BQ,4]
    float4* pcorn = (float4*)((char*)d_ws + (size_t)in_sizes[0] * sizeof(float));

    int n_cc = in_sizes[0];            // BQ*C
    int nprep = n_cc > BQ ? n_cc : BQ;
    prep_kernel<<<(nprep + 255) / 256, 256, 0, stream>>>(
        logits, pred_bbox, cc, pcorn, n_cc, BQ);

    int TG  = T / 4;                       // 400 target-groups
    int nTC = (TG + 63) / 64;              // 7 t-chunks
    int nBT = BQ / BQ_TILE;                // 900 bq tiles
    int nWU = nTC * nBT;                   // 6300 wave units
    int blocks = (nWU + 3) / 4;            // 4 waves per block
    cost_kernel<<<blocks, 256, 0, stream>>>(pred_bbox, pcorn, tgt_bbox, labels,
                                            cc, (float*)d_out, BQ, T, nTC, nWU);
}

// Round 13
// 116.408 us; speedup vs baseline: 1.0061x; 1.0061x over previous
//
#include <hip/hip_runtime.h>
#include <hip/hip_bf16.h>
#include <math.h>

#define ALPHA 0.25f
#define EPS 1e-8f
#define BQ_TILE 8

// ---------------------------------------------------------------------------
// Kernel 1: prep tables.
//  (a) per-(bq,c) focal class cost with GIoU-identity "+1" baked in
//  (b) per-bq pred corners {px0,py0,px1,py1}
// ---------------------------------------------------------------------------
__global__ __launch_bounds__(256) void prep_kernel(
    const float* __restrict__ logits,     // [BQ*C]
    const float* __restrict__ pred_bbox,  // [BQ,4]
    float* __restrict__ cc,               // [BQ*C] out: class cost + 1
    float4* __restrict__ pcorn,           // [BQ]   out: corners
    int n_cc, int BQ)
{
    int i = blockIdx.x * 256 + threadIdx.x;
    if (i < n_cc) {
        float x = logits[i];
        float p = 1.0f / (1.0f + expf(-x));
        float om = 1.0f - p;
        float pos = ALPHA * om * om * (-logf(p + EPS));
        float neg = (1.0f - ALPHA) * p * p * (-logf(om + EPS));
        cc[i] = pos - neg + 1.0f;
    }
    if (i < BQ) {
        float4 pb = reinterpret_cast<const float4*>(pred_bbox)[i];
        float4 c;
        c.x = pb.x - 0.5f * pb.z;
        c.y = pb.y - 0.5f * pb.w;
        c.z = pb.x + 0.5f * pb.z;
        c.w = pb.y + 0.5f * pb.w;
        pcorn[i] = c;
    }
}

// ---------------------------------------------------------------------------
// Kernel 2: pairwise cost [BQ, T].
//   cost = l1 + (cls+1) - (inter*ae + u^2)/(u*ae)   (exact; EPS terms cancel)
// BQ_TILE=8 -> 12600 wave-units (~12 waves/SIMD) for dep-latency hiding.
// 32-bit output indexing -> global_store_dwordx4 with SGPR base + voffset
// (no per-lane 64-bit address chain).
// ---------------------------------------------------------------------------
__global__ __launch_bounds__(256) void cost_kernel(
    const float* __restrict__ pred_bbox,  // [BQ,4] cxcywh
    const float4* __restrict__ pcorn,     // [BQ]   corners
    const float* __restrict__ tgt_bbox,   // [T,4]  cxcywh
    const int*   __restrict__ labels,     // [T]
    const float* __restrict__ cc,         // [BQ,4] class cost + 1
    float* __restrict__ out,              // [BQ,T]
    int BQ, int T, int nTC, int nWU)
{
    __shared__ float s_cc[4 * BQ_TILE * 4];   // [wave][8 bq][4 classes]

    int wslot = threadIdx.x >> 6;
    int lane  = threadIdx.x & 63;
    int wu = blockIdx.x * 4 + wslot;
    wu = __builtin_amdgcn_readfirstlane(wu);   // SGPR: scalar loads + SALU idx
    if (wu >= nWU) return;
    int tc  = wu % nTC;          // t-chunk (64 tgroups each)
    int bqt = wu / nTC;          // bq tile (8 rows)
    int bq0 = bqt * BQ_TILE;

    // stage this wave's 32-float class-cost slice (same-wave use -> no barrier)
    if (lane < BQ_TILE * 4)
        s_cc[wslot * (BQ_TILE * 4) + lane] = cc[bq0 * 4 + lane];

    int tg = tc * 64 + lane;     // target-group index (4 targets each)
    int TG = T >> 2;
    if (tg >= TG) return;
    int t0 = tg * 4;

    // ---- target-side setup: 4 targets per thread (hoisted) ----
    float4 tb[4];
    float tx0[4], ty0[4], tx1[4], ty1[4], a2e[4];
    int lidx[4];
    int4 lv = reinterpret_cast<const int4*>(labels)[tg];
    int lbl[4] = {lv.x, lv.y, lv.z, lv.w};
    #pragma unroll
    for (int j = 0; j < 4; ++j) {
        tb[j] = reinterpret_cast<const float4*>(tgt_bbox)[t0 + j];
        tx0[j] = tb[j].x - 0.5f * tb[j].z;
        ty0[j] = tb[j].y - 0.5f * tb[j].w;
        tx1[j] = tb[j].x + 0.5f * tb[j].z;
        ty1[j] = tb[j].y + 0.5f * tb[j].w;
        a2e[j] = tb[j].z * tb[j].w + EPS;          // area2 + EPS pre-folded
        lidx[j] = wslot * (BQ_TILE * 4) + lbl[j];  // LDS base (bq adds i*4)
    }

    int obase = bq0 * T + t0;    // 32-bit: max 23.04M, fits easily

    #pragma unroll
    for (int i = 0; i < BQ_TILE; ++i) {            // no break: BQ % 8 == 0
        int bq = bq0 + i;
        // wave-uniform -> scalar s_load pair, pipelined across the unroll
        float4 pb = reinterpret_cast<const float4*>(pred_bbox)[bq];
        float4 pc = pcorn[bq];
        float area1 = pb.z * pb.w;

        float r[4];
        #pragma unroll
        for (int j = 0; j < 4; ++j) {
            // class cost (+1): LDS gather, immediate offset i*16B, 0 VALU
            float cls = s_cc[lidx[j] + i * 4];

            // L1 on cxcywh
            float l1 = (fabsf(pb.x - tb[j].x) + fabsf(pb.y - tb[j].y))
                     + (fabsf(pb.z - tb[j].z) + fabsf(pb.w - tb[j].w));

            // intersection (raw widths kept for enclosing-box identity)
            float iwr = fminf(pc.z, tx1[j]) - fmaxf(pc.x, tx0[j]);
            float ihr = fminf(pc.w, ty1[j]) - fmaxf(pc.y, ty0[j]);
            float iw = fmaxf(iwr, 0.0f);
            float ih = fmaxf(ihr, 0.0f);
            float inter = iw * ih;

            // enclosing box via min+max=sum identity
            float ew = (pb.z + tb[j].z) - iwr;
            float eh = (pb.w + tb[j].w) - ihr;
            float ae = fmaf(ew, eh, EPS);          // area_e + EPS

            float u = (area1 + a2e[j]) - inter;    // union + EPS

            // inter/u + u/ae == (inter*ae + u*u)/(u*ae) -- one rcp
            float num = fmaf(inter, ae, u * u);
            float q = num * __builtin_amdgcn_rcpf(u * ae);

            r[j] = (l1 + cls) - q;
        }
        *reinterpret_cast<float4*>(&out[obase + i * T]) =
            make_float4(r[0], r[1], r[2], r[3]);
    }
}

extern "C" void kernel_launch(void* const* d_in, const int* in_sizes, int n_in,
                              void* d_out, int out_size, void* d_ws, size_t ws_size,
                              hipStream_t stream) {
    const float* logits    = (const float*)d_in[0];  // [B,Q,C]
    const float* pred_bbox = (const float*)d_in[1];  // [B,Q,4]
    const float* tgt_bbox  = (const float*)d_in[2];  // [T,4]
    const int*   labels    = (const int*)d_in[3];    // [T]

    int BQ = in_sizes[1] / 4;          // 14400
    int T  = in_sizes[3];              // 1600

    float*  cc    = (float*)d_ws;                    // [BQ,4]
    float4* pcorn = (float4*)((char*)d_ws + (size_t)in_sizes[0] * sizeof(float));

    int n_cc = in_sizes[0];            // BQ*C
    int nprep = n_cc > BQ ? n_cc : BQ;
    prep_kernel<<<(nprep + 255) / 256, 256, 0, stream>>>(
        logits, pred_bbox, cc, pcorn, n_cc, BQ);

    int TG  = T / 4;                       // 400 target-groups
    int nTC = (TG + 63) / 64;              // 7 t-chunks
    int nBT = BQ / BQ_TILE;                // 1800 bq tiles
    int nWU = nTC * nBT;                   // 12600 wave units
    int blocks = (nWU + 3) / 4;            // 4 waves per block
    cost_kernel<<<blocks, 256, 0, stream>>>(pred_bbox, pcorn, tgt_bbox, labels,
                                            cc, (float*)d_out, BQ, T, nTC, nWU);
}